// Round 9
// baseline (77.099 us; speedup 1.0000x reference)
//
#include <hip/hip_runtime.h>
#include <hip/hip_bf16.h>
#include <stdint.h>

// ---------------------------------------------------------------------------
// MatrixDFTLayer: out[b,k,c] = sum_n x[b,n] * (c==0 ? R : I)[k,n],  x REAL.
// Hermitian: Y[1024-k] = conj(Y[k]) -> GEMM k=0..511 only; epilogue mirrors.
// R9: fuse x->bf16 into GEMM A-staging (reg-stage: fp32 loads -> cvt ->
// swizzled ds_write). Kills the convert pass's 100 MB x round-trip.
// Nyquist row folded into Beff row 1 (was k=0's all-zero imag row):
// Beff[1][n] = (-1)^n, epilogue routes col1 -> C col 1024, zeroes cols 1/1025.
// B staging stays glds; publish discipline: compiler's implicit in-order
// vmcnt waits at cvt sites + lgkmcnt(0) before closing barriers (T14).
// ---------------------------------------------------------------------------

typedef __bf16 bf16x8 __attribute__((ext_vector_type(8)));
typedef float f32x4 __attribute__((ext_vector_type(4)));
typedef unsigned short ushort8 __attribute__((ext_vector_type(8)));

#define M_DIM   16384
#define N_OUT   2048          // C row stride (floats)
#define K_DIM   1024
#define NT      16            // K tiles of BK=64
#define BH_ELEMS 1048576ull   // 1024*1024 (half-spectrum Beff)

__device__ __forceinline__ unsigned short f2bf(float f) {
    union { float f; unsigned u; } v; v.f = f;
    unsigned r = v.u + 0x7fffu + ((v.u >> 16) & 1u);   // RTNE
    return (unsigned short)(r >> 16);
}

// ---- pre-pass: build Beff only (2 MB). Row j: j==1 -> Nyquist (+-1);
// else k=j>>1, c=j&1 -> (c? I : R) row k.  Rows j=0..1023 cover k=0..511. ---
__global__ __launch_bounds__(256) void convert_B(
    const float* __restrict__ R, const float* __restrict__ Im,
    unsigned short* __restrict__ Beff)
{
    size_t idx = ((size_t)blockIdx.x * 256 + threadIdx.x) * 8;
    size_t j = idx >> 10, n = idx & 1023;
    ushort8 o;
    if (j == 1) {
        o = (ushort8){0x3F80u, 0xBF80u, 0x3F80u, 0xBF80u,
                      0x3F80u, 0xBF80u, 0x3F80u, 0xBF80u};   // (-1)^n
    } else {
        const float* src = ((j & 1) ? Im : R) + (j >> 1) * 1024 + n;
        float4 f0 = *(const float4*)src;
        float4 f1 = *(const float4*)(src + 4);
        o[0] = f2bf(f0.x); o[1] = f2bf(f0.y); o[2] = f2bf(f0.z); o[3] = f2bf(f0.w);
        o[4] = f2bf(f1.x); o[5] = f2bf(f1.y); o[6] = f2bf(f1.z); o[7] = f2bf(f1.w);
    }
    *(ushort8*)(Beff + idx) = o;
}

#define GLOAD_LDS16(g, l) \
    __builtin_amdgcn_global_load_lds( \
        (const __attribute__((address_space(1))) void*)(g), \
        (__attribute__((address_space(3))) void*)(l), 16, 0, 0)

// ---------------------------------------------------------------------------
// 256x256 tile, BK=64, 8 waves (2Mx4N), double-buffered LDS (128 KiB),
// 4 phases/K-tile. A: reg-staged from fp32 x with cvt (issue A0@q0, A1@q1;
// cvt+ds_write A0@q2, A1@q3 -- implicit in-order vmcnt waits retire tile
// t+1's loads, leave B0(t+2) in flight). B: glds, B1(t+1)@q0, B0(t+2)@q3.
// lgkmcnt(0) before closing barriers of q2/q3 publishes the ds_writes.
// XOR swizzle invariant (both paths): LDS[r][slot s] = G[r][s ^ sx(r)],
// sx(r) = (r&3) | (((r>>2)&1)<<2).
// ---------------------------------------------------------------------------
__global__ __launch_bounds__(512, 1) void dft_gemm256(
    const float* __restrict__ X,            // [16384][1024] fp32
    const unsigned short* __restrict__ Bm,  // [1024][1024]  bf16 bits
    float* __restrict__ C)                  // [16384][2048] fp32
{
    __shared__ __align__(16) unsigned short lds[2][2][16384];

    const int tid  = threadIdx.x;
    const int lane = tid & 63;
    const int w    = tid >> 6;          // wave 0..7
    const int wr   = w >> 2;            // 0..1 (M)
    const int wc   = w & 3;             // 0..3 (N)

    const int bid = blockIdx.x;
    const int swz = (bid & 7) * 32 + (bid >> 3);
    const int tn  = swz & 3;            // 4 col tiles (1024/256)
    const int tm  = swz >> 2;           // 64 row tiles (same tm -> same XCD)

    // ---- B staging constants (pre-swizzled global source, linear dest) ----
    const int r3    = lane >> 3;
    const int fx_w  = ((r3 & 3) << 4) | (((r3 >> 2) & 1) << 6);
    const int scol  = ((((lane & 7) * 16) ^ fx_w) >> 1);
    const int srow  = w * 8 + r3;
    const size_t b_row0 = (size_t)(tn * 256) * K_DIM;

    auto stage_B = [&](int buf, int half, int kt) {
        const unsigned short* g = Bm + b_row0
            + (size_t)(half * 128 + srow) * K_DIM + kt * 64 + scol;
        unsigned short* l0 = &lds[buf][1][half * 8192 + w * 512];
        GLOAD_LDS16(g,              l0);
        GLOAD_LDS16(g + 64 * K_DIM, l0 + 4096);
    };

    // ---- A staging constants (fp32 reg-stage + cvt + swizzled ds_write) ---
    // thread: row a_r = tid>>2 (0..127 within half), colgroup a_cg = tid&3
    const int a_r  = tid >> 2;
    const int a_cg = tid & 3;
    const int a_sx = (a_r & 3) | (((a_r >> 2) & 1) << 2);
    const int e_lo = ((2 * a_cg)     ^ a_sx) * 8;   // elem offset in row
    const int e_hi = ((2 * a_cg + 1) ^ a_sx) * 8;
    const size_t a_base = (size_t)(tm * 256 + a_r) * K_DIM + a_cg * 16;

    auto issue_A = [&](float4* ar, int half, int kt) {
        const float* g = X + a_base + (size_t)half * (128 * K_DIM) + kt * 64;
        ar[0] = *(const float4*)(g);
        ar[1] = *(const float4*)(g + 4);
        ar[2] = *(const float4*)(g + 8);
        ar[3] = *(const float4*)(g + 12);
    };
    auto write_A = [&](const float4* ar, int buf, int half) {
        bf16x8 lo, hi;
        lo[0] = (__bf16)ar[0].x; lo[1] = (__bf16)ar[0].y;
        lo[2] = (__bf16)ar[0].z; lo[3] = (__bf16)ar[0].w;
        lo[4] = (__bf16)ar[1].x; lo[5] = (__bf16)ar[1].y;
        lo[6] = (__bf16)ar[1].z; lo[7] = (__bf16)ar[1].w;
        hi[0] = (__bf16)ar[2].x; hi[1] = (__bf16)ar[2].y;
        hi[2] = (__bf16)ar[2].z; hi[3] = (__bf16)ar[2].w;
        hi[4] = (__bf16)ar[3].x; hi[5] = (__bf16)ar[3].y;
        hi[6] = (__bf16)ar[3].z; hi[7] = (__bf16)ar[3].w;
        unsigned short* bp = &lds[buf][0][half * 8192 + a_r * 64];
        *(bf16x8*)(bp + e_lo) = lo;
        *(bf16x8*)(bp + e_hi) = hi;
    };

    // ---- fragment-read constants (swizzled ds_read, unchanged) ------------
    const int fx_r = ((lane & 3) << 4) | (((lane >> 2) & 1) << 6);
    const int e0   = ((((lane >> 4) & 3) * 16) ^ fx_r) >> 1;        // ks0
    const int e1   = ((64 + ((lane >> 4) & 3) * 16) ^ fx_r) >> 1;   // ks1
    const int arow = (wr * 128 + (lane & 15)) * 64;
    const int brow = (wc * 64  + (lane & 15)) * 64;

    f32x4 acc[8][4];
#pragma unroll
    for (int i = 0; i < 8; ++i)
#pragma unroll
        for (int j = 0; j < 4; ++j)
            acc[i][j] = (f32x4){0.f, 0.f, 0.f, 0.f};

    float4 arA[4], arB[4];

    // ---- prologue: tile0 (B glds + A reg-stage) + B0(1); publish ----------
    stage_B(0, 0, 0); stage_B(0, 1, 0);
    issue_A(arA, 0, 0); issue_A(arB, 1, 0);
    write_A(arA, 0, 0);              // implicit vmcnt wait (retires B(0) too)
    write_A(arB, 0, 1);
    stage_B(1, 0, 1);                // B0(1), stays in flight
    asm volatile("s_waitcnt lgkmcnt(0)" ::: "memory");
    __builtin_amdgcn_s_barrier();

    bf16x8 af[4], bf[4];
    int buf = 0;
    for (int t = 0; t < NT; ++t) {
        const int nbuf = buf ^ 1;

        // ===== q0: acc[0-3] ks0; stage B1(t+1) glds; issue A0(t+1) =====
#pragma unroll
        for (int i = 0; i < 4; ++i)
            af[i] = *(const bf16x8*)&lds[buf][0][arow + i * 1024 + e0];
#pragma unroll
        for (int j = 0; j < 4; ++j)
            bf[j] = *(const bf16x8*)&lds[buf][1][brow + j * 1024 + e0];
        if (t + 1 < NT) { stage_B(nbuf, 1, t + 1); issue_A(arA, 0, t + 1); }
        __builtin_amdgcn_s_barrier();
        __builtin_amdgcn_s_setprio(1);
#pragma unroll
        for (int i = 0; i < 4; ++i)
#pragma unroll
            for (int j = 0; j < 4; ++j)
                acc[i][j] = __builtin_amdgcn_mfma_f32_16x16x32_bf16(
                    af[i], bf[j], acc[i][j], 0, 0, 0);
        __builtin_amdgcn_s_setprio(0);
        __builtin_amdgcn_s_barrier();

        // ===== q1: acc[4-7] ks0; issue A1(t+1) =====
#pragma unroll
        for (int i = 0; i < 4; ++i)
            af[i] = *(const bf16x8*)&lds[buf][0][arow + (i + 4) * 1024 + e0];
        if (t + 1 < NT) issue_A(arB, 1, t + 1);
        __builtin_amdgcn_s_barrier();
        __builtin_amdgcn_s_setprio(1);
#pragma unroll
        for (int i = 0; i < 4; ++i)
#pragma unroll
            for (int j = 0; j < 4; ++j)
                acc[i + 4][j] = __builtin_amdgcn_mfma_f32_16x16x32_bf16(
                    af[i], bf[j], acc[i + 4][j], 0, 0, 0);
        __builtin_amdgcn_s_setprio(0);
        __builtin_amdgcn_s_barrier();

        // ===== q2: acc[0-3] ks1; cvt+write A0(t+1) [vmcnt(4) implicit] =====
        // WAR ok: nbuf A-half0 last read at t-1 q3 (two barriers back).
#pragma unroll
        for (int i = 0; i < 4; ++i)
            af[i] = *(const bf16x8*)&lds[buf][0][arow + i * 1024 + e1];
#pragma unroll
        for (int j = 0; j < 4; ++j)
            bf[j] = *(const bf16x8*)&lds[buf][1][brow + j * 1024 + e1];
        if (t + 1 < NT) write_A(arA, nbuf, 0);
        __builtin_amdgcn_s_barrier();
        __builtin_amdgcn_s_setprio(1);
#pragma unroll
        for (int i = 0; i < 4; ++i)
#pragma unroll
            for (int j = 0; j < 4; ++j)
                acc[i][j] = __builtin_amdgcn_mfma_f32_16x16x32_bf16(
                    af[i], bf[j], acc[i][j], 0, 0, 0);
        __builtin_amdgcn_s_setprio(0);
        asm volatile("s_waitcnt lgkmcnt(0)" ::: "memory");   // publish A0 writes
        __builtin_amdgcn_s_barrier();

        // ===== q3: acc[4-7] ks1; cvt+write A1(t+1); stage B0(t+2) =====
        // cvt's implicit vmcnt wait (in-order) retires ALL of tile t+1's
        // loads incl. B glds; B0(t+2), issued after, stays in flight.
#pragma unroll
        for (int i = 0; i < 4; ++i)
            af[i] = *(const bf16x8*)&lds[buf][0][arow + (i + 4) * 1024 + e1];
        if (t + 1 < NT) write_A(arB, nbuf, 1);
        if (t + 2 < NT) stage_B(buf, 0, t + 2);
        if (t + 2 < NT)      asm volatile("s_waitcnt vmcnt(2)" ::: "memory");
        else if (t + 1 < NT) asm volatile("s_waitcnt vmcnt(0)" ::: "memory");
        __builtin_amdgcn_s_barrier();
        __builtin_amdgcn_s_setprio(1);
#pragma unroll
        for (int i = 0; i < 4; ++i)
#pragma unroll
            for (int j = 0; j < 4; ++j)
                acc[i + 4][j] = __builtin_amdgcn_mfma_f32_16x16x32_bf16(
                    af[i], bf[j], acc[i + 4][j], 0, 0, 0);
        __builtin_amdgcn_s_setprio(0);
        asm volatile("s_waitcnt lgkmcnt(0)" ::: "memory");   // publish A1 writes
        __builtin_amdgcn_s_barrier();

        buf = nbuf;
    }

    // ---- epilogue: primary + Hermitian mirror; col0/col1 special ----------
    // col j>=2: primary col j, mirror 2048-j+2*(j&1) with sign -(j&1).
    // col 0: Y_r[0] only. col 1: Nyquist real -> C col 1024; cols 1,1025 = 0.
    const int crow0 = tm * 256 + wr * 128 + ((lane >> 4) << 2);
    const int ccol0 = tn * 256 + wc * 64 + (lane & 15);
#pragma unroll
    for (int i = 0; i < 8; ++i)
#pragma unroll
        for (int j = 0; j < 4; ++j) {
            const int col = ccol0 + j * 16;
            float* rowp = C + (size_t)(crow0 + i * 16) * N_OUT;
            if (col >= 2) {
                const int   mcol = 2048 - col + 2 * (col & 1);
                const float ms   = (col & 1) ? -1.0f : 1.0f;
#pragma unroll
                for (int r = 0; r < 4; ++r) {
                    rowp[(size_t)r * N_OUT + col]  = acc[i][j][r];
                    rowp[(size_t)r * N_OUT + mcol] = ms * acc[i][j][r];
                }
            } else if (col == 0) {
#pragma unroll
                for (int r = 0; r < 4; ++r)
                    rowp[(size_t)r * N_OUT] = acc[i][j][r];
            } else {   // col == 1: Nyquist real
#pragma unroll
                for (int r = 0; r < 4; ++r) {
                    rowp[(size_t)r * N_OUT + 1024] = acc[i][j][r];
                    rowp[(size_t)r * N_OUT + 1]    = 0.0f;
                    rowp[(size_t)r * N_OUT + 1025] = 0.0f;
                }
            }
        }
}

// ---- fallback (only if d_ws is too small): naive fp32 ----
__global__ void naive_dft(const float* __restrict__ x, const float* __restrict__ R,
                          const float* __restrict__ Im, float* __restrict__ out)
{
    int gid = blockIdx.x * blockDim.x + threadIdx.x;
    int b = gid >> 10, k = gid & 1023;
    const float* xr = x + (size_t)b * 1024;
    const float* rr = R + (size_t)k * 1024;
    const float* ir = Im + (size_t)k * 1024;
    float sr = 0.f, si = 0.f;
    for (int n = 0; n < 1024; ++n) {
        float v = xr[n];
        sr += v * rr[n];
        si += v * ir[n];
    }
    out[(size_t)gid * 2]     = sr;
    out[(size_t)gid * 2 + 1] = si;
}

extern "C" void kernel_launch(void* const* d_in, const int* in_sizes, int n_in,
                              void* d_out, int out_size, void* d_ws, size_t ws_size,
                              hipStream_t stream)
{
    const float* x  = (const float*)d_in[0];
    const float* R  = (const float*)d_in[1];
    const float* Im = (const float*)d_in[2];
    float* out = (float*)d_out;

    const size_t need = BH_ELEMS * sizeof(unsigned short);   // 2 MB
    if (ws_size >= need) {
        unsigned short* Beff = (unsigned short*)d_ws;
        convert_B<<<512, 256, 0, stream>>>(R, Im, Beff);
        dft_gemm256<<<256, 512, 0, stream>>>(x, Beff, out);
    } else {
        naive_dft<<<(M_DIM * K_DIM) / 256, 256, 0, stream>>>(x, R, Im, out);
    }
}

// Round 10
// 73.882 us; speedup vs baseline: 1.0435x; 1.0435x over previous
//
#include <hip/hip_runtime.h>
#include <hip/hip_bf16.h>
#include <stdint.h>

// ---------------------------------------------------------------------------
// MatrixDFTLayer: out[b,k,c] = sum_n x[b,n] * (c==0 ? R : I)[k,n],  x REAL.
// Hermitian: Y[1024-k] = conj(Y[k]) -> GEMM k=0..511 only; epilogue mirrors;
// Nyquist fused in convert (R8-validated). R10: GEMM = m97-shape 128x128
// tile, BK=32, 4 waves, ONE barrier/tile, 32 KB dbuf LDS -> 4 blocks/CU
// (grid 1024): deep co-residency staggers epilogue bursts / prologues /
// vmcnt drains across blocks (R9 lesson: reg-stage fusion = -26us; R6's
// co-residency test was confounded by 2-round lockstep at full FLOPs).
// ---------------------------------------------------------------------------

typedef __bf16 bf16x8 __attribute__((ext_vector_type(8)));
typedef float f32x4 __attribute__((ext_vector_type(4)));
typedef unsigned short ushort8 __attribute__((ext_vector_type(8)));

#define M_DIM   16384
#define N_OUT   2048          // C row stride (floats)
#define K_DIM   1024
#define NT      32            // K tiles of BK=32
#define X_ELEMS 16777216ull   // 16384*1024
#define BH_ELEMS 1048576ull   // 1024*1024 (half-spectrum Beff)

__device__ __forceinline__ unsigned short f2bf(float f) {
    union { float f; unsigned u; } v; v.f = f;
    unsigned r = v.u + 0x7fffu + ((v.u >> 16) & 1u);   // RTNE
    return (unsigned short)(r >> 16);
}

// ---- pre-pass (R8-validated): x->bf16, gather k<512 R/I rows -> Beff,
// fused Nyquist yr[b,512] = sum_n x[b,n]*(-1)^n (yi = 0). -------------------
__global__ __launch_bounds__(256) void convert_kernel(
    const float* __restrict__ x, const float* __restrict__ R,
    const float* __restrict__ Im,
    unsigned short* __restrict__ xa, unsigned short* __restrict__ Beff,
    float* __restrict__ C)
{
    __shared__ float nsum[4];
    size_t idx = ((size_t)blockIdx.x * 256 + threadIdx.x) * 8;
    const float* src;
    unsigned short* dst;
    if (idx < X_ELEMS) {
        src = x + idx;
        dst = xa + idx;
    } else {
        size_t t = idx - X_ELEMS;          // linear index in Beff (1024x1024)
        size_t j = t >> 10, n = t & 1023;  // Beff row j = 2k+c, col n
        src = ((j & 1) ? Im : R) + (j >> 1) * 1024 + n;
        dst = Beff + t;
    }
    float4 f0 = *(const float4*)src;
    float4 f1 = *(const float4*)(src + 4);
    ushort8 o;
    o[0] = f2bf(f0.x); o[1] = f2bf(f0.y); o[2] = f2bf(f0.z); o[3] = f2bf(f0.w);
    o[4] = f2bf(f1.x); o[5] = f2bf(f1.y); o[6] = f2bf(f1.z); o[7] = f2bf(f1.w);
    *(ushort8*)dst = o;

    if (blockIdx.x < 8192) {
        float s = f0.x - f0.y + f0.z - f0.w + f1.x - f1.y + f1.z - f1.w;
#pragma unroll
        for (int m = 32; m >= 1; m >>= 1)
            s += __shfl_xor(s, m, 64);
        const int w = threadIdx.x >> 6;     // wave 0..3
        if ((threadIdx.x & 63) == 0) nsum[w] = s;
        __syncthreads();
        if (threadIdx.x == 0) {
            size_t row = (size_t)blockIdx.x * 2;
            C[row * N_OUT + 1024] = nsum[0] + nsum[1];
            C[row * N_OUT + 1025] = 0.0f;
        }
        if (threadIdx.x == 128) {
            size_t row = (size_t)blockIdx.x * 2 + 1;
            C[row * N_OUT + 1024] = nsum[2] + nsum[3];
            C[row * N_OUT + 1025] = 0.0f;
        }
    }
}

#define GLOAD_LDS16(g, l) \
    __builtin_amdgcn_global_load_lds( \
        (const __attribute__((address_space(1))) void*)(g), \
        (__attribute__((address_space(3))) void*)(l), 16, 0, 0)

// ---------------------------------------------------------------------------
// 128x128 tile, BK=32, 4 waves (2Mx2N, 64x64 out each), double-buffered
// 32 KB LDS, ONE barrier per K-tile (m97/T3 minimal recipe):
//   reads(buf) ; stage(nbuf,t+1) ; [compiler lgkm] MFMA x16 ; vmcnt(0) ;
//   barrier
// WAR: nbuf's tile-(t-1) readers retired their ds_reads (lgkm before their
// MFMAs) before tile-(t-1)'s closing barrier. RAW: vmcnt(0)+barrier ensure
// nbuf staged before tile t+1 reads. 4 blocks/CU hide the drain.
// Swizzle (R6-validated, 64B rows): slot' = slot ^ ((row>>1)&3), applied
// pre-swizzled on the glds global source + same XOR on ds_read; dest linear.
// ---------------------------------------------------------------------------
__global__ __launch_bounds__(256, 4) void dft_gemm128(
    const unsigned short* __restrict__ A,   // xa [16384][1024] bf16 bits
    const unsigned short* __restrict__ Bm,  // Beff [1024][1024] bf16 bits
    float* __restrict__ C)                  // [16384][2048] fp32
{
    __shared__ __align__(16) unsigned short lds[2][2][4096];  // 32 KB

    const int tid  = threadIdx.x;
    const int lane = tid & 63;
    const int w    = tid >> 6;          // wave 0..3
    const int wr   = w >> 1;            // 0..1 (M)
    const int wc   = w & 1;             // 0..1 (N)

    // XCD swizzle: nwg=1024 divisible by 8; 8 tn-blocks of a tm share an XCD
    const int bid = blockIdx.x;
    const int swz = (bid & 7) * 128 + (bid >> 3);
    const int tn  = swz & 7;            // 8 col tiles (1024/128)
    const int tm  = swz >> 3;           // 128 row tiles (16384/128)

    // ---- staging (R6-validated formulas): thread t -> row t>>2, slot t&3;
    // source slot pre-swizzled: (t&3) ^ ((t>>3)&3); dest linear. -----------
    const int srow = tid >> 2;                         // 0..63
    const int scol = ((tid & 3) ^ ((tid >> 3) & 3)) * 8;
    const size_t a_row0 = (size_t)(tm * 128) * K_DIM;
    const size_t b_row0 = (size_t)(tn * 128) * K_DIM;

    auto stage = [&](int buf, int op, int kt) {        // one 128x32 tile
        const unsigned short* g = (op ? Bm + b_row0 : A + a_row0)
            + (size_t)srow * K_DIM + kt * 32 + scol;
        unsigned short* l0 = &lds[buf][op][w * 512];
        GLOAD_LDS16(g,                 l0);
        GLOAD_LDS16(g + 64 * K_DIM,    l0 + 2048);     // rows 64..127
    };

    // ---- fragment reads: row = base + (lane&15) + i*16, k-slot lane>>4;
    // swizzled elem offset: ((lane>>4) ^ ((row>>1)&3)) * 8  [R6-validated] --
    const int e    = ((lane >> 4) ^ ((lane >> 1) & 3)) * 8;
    const int arow = (wr * 64 + (lane & 15)) * 32;
    const int brow = (wc * 64 + (lane & 15)) * 32;

    f32x4 acc[4][4];
#pragma unroll
    for (int i = 0; i < 4; ++i)
#pragma unroll
        for (int j = 0; j < 4; ++j)
            acc[i][j] = (f32x4){0.f, 0.f, 0.f, 0.f};

    // ---- prologue: tile 0 staged, drained, barrier ------------------------
    stage(0, 0, 0); stage(0, 1, 0);
    asm volatile("s_waitcnt vmcnt(0)" ::: "memory");
    __builtin_amdgcn_s_barrier();

    bf16x8 af[4], bf[4];
    int buf = 0;
    for (int t = 0; t < NT; ++t) {
        const int nbuf = buf ^ 1;

#pragma unroll
        for (int i = 0; i < 4; ++i)
            af[i] = *(const bf16x8*)&lds[buf][0][arow + i * 512 + e];
#pragma unroll
        for (int j = 0; j < 4; ++j)
            bf[j] = *(const bf16x8*)&lds[buf][1][brow + j * 512 + e];
        if (t + 1 < NT) { stage(nbuf, 0, t + 1); stage(nbuf, 1, t + 1); }

        __builtin_amdgcn_s_setprio(1);
#pragma unroll
        for (int i = 0; i < 4; ++i)
#pragma unroll
            for (int j = 0; j < 4; ++j)
                acc[i][j] = __builtin_amdgcn_mfma_f32_16x16x32_bf16(
                    af[i], bf[j], acc[i][j], 0, 0, 0);
        __builtin_amdgcn_s_setprio(0);

        asm volatile("s_waitcnt vmcnt(0)" ::: "memory");
        __builtin_amdgcn_s_barrier();
        buf = nbuf;
    }

    // ---- epilogue: primary (cols 0..1023) + Hermitian mirror --------------
    // C/D layout: col = lane&15, row = (lane>>4)*4 + reg  [m89]
    // col j>=2: mirror m = 2048 - j + 2*(j&1), sign -(j&1). cols 0,1 primary
    // only (col1 = imag Y[0] = 0 from zero Beff row 1). Convert owns 1024/5.
    const int crow0 = tm * 128 + wr * 64 + ((lane >> 4) << 2);
    const int ccol0 = tn * 128 + wc * 64 + (lane & 15);
#pragma unroll
    for (int i = 0; i < 4; ++i)
#pragma unroll
        for (int j = 0; j < 4; ++j) {
            const int   col   = ccol0 + j * 16;
            const int   mcol  = 2048 - col + 2 * (col & 1);
            const float msign = (col & 1) ? -1.0f : 1.0f;
            const bool  do_m  = (col >= 2);
            float* cp = C + (size_t)(crow0 + i * 16) * N_OUT + col;
            float* mp = C + (size_t)(crow0 + i * 16) * N_OUT + mcol;
#pragma unroll
            for (int r = 0; r < 4; ++r) {
                cp[(size_t)r * N_OUT] = acc[i][j][r];
                if (do_m) mp[(size_t)r * N_OUT] = msign * acc[i][j][r];
            }
        }
}

// ---- fallback (only if d_ws is too small): naive fp32 ----
__global__ void naive_dft(const float* __restrict__ x, const float* __restrict__ R,
                          const float* __restrict__ Im, float* __restrict__ out)
{
    int gid = blockIdx.x * blockDim.x + threadIdx.x;
    int b = gid >> 10, k = gid & 1023;
    const float* xr = x + (size_t)b * 1024;
    const float* rr = R + (size_t)k * 1024;
    const float* ir = Im + (size_t)k * 1024;
    float sr = 0.f, si = 0.f;
    for (int n = 0; n < 1024; ++n) {
        float v = xr[n];
        sr += v * rr[n];
        si += v * ir[n];
    }
    out[(size_t)gid * 2]     = sr;
    out[(size_t)gid * 2 + 1] = si;
}

extern "C" void kernel_launch(void* const* d_in, const int* in_sizes, int n_in,
                              void* d_out, int out_size, void* d_ws, size_t ws_size,
                              hipStream_t stream)
{
    const float* x  = (const float*)d_in[0];
    const float* R  = (const float*)d_in[1];
    const float* Im = (const float*)d_in[2];
    float* out = (float*)d_out;

    const size_t need = (X_ELEMS + BH_ELEMS) * sizeof(unsigned short); // 35.7 MB
    if (ws_size >= need) {
        unsigned short* xa   = (unsigned short*)d_ws;
        unsigned short* Beff = xa + X_ELEMS;
        const int conv_blocks = (int)((X_ELEMS + BH_ELEMS) / 8 / 256); // 8704
        convert_kernel<<<conv_blocks, 256, 0, stream>>>(x, R, Im, xa, Beff, out);
        dft_gemm128<<<1024, 256, 0, stream>>>(xa, Beff, out);
    } else {
        naive_dft<<<(M_DIM * K_DIM) / 256, 256, 0, stream>>>(x, R, Im, out);
    }
}